// Round 1
// baseline (329.962 us; speedup 1.0000x reference)
//
#include <hip/hip_runtime.h>
#include <hip/hip_bf16.h>

#define SUP 2048

// ---------------------------------------------------------------------------
// K1: per-pixel inverse L2 norm over the 32 conv channels.
// conv layout [C=32][npix]; thread i handles pixel i (coalesced per channel).
// ---------------------------------------------------------------------------
__global__ __launch_bounds__(256) void k_invnorm(const float* __restrict__ conv,
                                                 float* __restrict__ inv,
                                                 int npix) {
    int i = blockIdx.x * blockDim.x + threadIdx.x;
    if (i >= npix) return;
    float s = 0.f;
#pragma unroll
    for (int c = 0; c < 32; ++c) {
        float v = conv[c * npix + i];
        s += v * v;
    }
    inv[i] = 1.0f / fmaxf(sqrtf(s), 1e-12f);
}

// ---------------------------------------------------------------------------
// K2: segment accumulation with LDS privatization.
// gridDim.y = 5 groups: g=0..3 -> conv channels [g*8, g*8+8), normalized by inv;
//                       g=4    -> x channels (3) + count.
// LDS layout: sacc[c][SUP] (bank = s % 32, random -> ~2-way, free).
// Flush: coalesced global f32 atomics into accum[36][SUP].
// ---------------------------------------------------------------------------
__global__ __launch_bounds__(512) void k_segacc(const float* __restrict__ conv,
                                                const float* __restrict__ x,
                                                const int* __restrict__ ids,
                                                const float* __restrict__ inv,
                                                float* __restrict__ accum,
                                                int npix) {
    __shared__ float sacc[8 * SUP];  // 64 KiB
    int g = blockIdx.y;
    int nsl = (g < 4) ? 8 * SUP : 4 * SUP;
    for (int i = threadIdx.x; i < nsl; i += blockDim.x) sacc[i] = 0.f;
    __syncthreads();

    int per = (npix + gridDim.x - 1) / gridDim.x;
    int start = blockIdx.x * per;
    int end = min(start + per, npix);

    if (g < 4) {
        const float* c0 = conv + g * 8 * npix;
        for (int p = start + (int)threadIdx.x; p < end; p += blockDim.x) {
            int s = ids[p];
            float w = inv[p];
#pragma unroll
            for (int c = 0; c < 8; ++c) {
                unsafeAtomicAdd(&sacc[c * SUP + s], c0[c * npix + p] * w);
            }
        }
    } else {
        for (int p = start + (int)threadIdx.x; p < end; p += blockDim.x) {
            int s = ids[p];
            unsafeAtomicAdd(&sacc[0 * SUP + s], x[p]);
            unsafeAtomicAdd(&sacc[1 * SUP + s], x[npix + p]);
            unsafeAtomicAdd(&sacc[2 * SUP + s], x[2 * npix + p]);
            unsafeAtomicAdd(&sacc[3 * SUP + s], 1.0f);
        }
    }
    __syncthreads();

    int base = (g < 4) ? g * 8 * SUP : 32 * SUP;
    for (int i = threadIdx.x; i < nsl; i += blockDim.x) {
        unsafeAtomicAdd(&accum[base + i], sacc[i]);
    }
}

// ---------------------------------------------------------------------------
// K3: per-segment finalize. accum[36][SUP]: rows 0..31 conv sums, 32..34 x sums,
// 35 count. Computes M_F, vit_n, all_F = l2norm(concat) -> out, X_F -> out.
// ---------------------------------------------------------------------------
__global__ __launch_bounds__(256) void k_final(const float* __restrict__ accum,
                                               const float* __restrict__ vit,
                                               float* __restrict__ allF_out,
                                               float* __restrict__ xf_out) {
    int s = blockIdx.x * blockDim.x + threadIdx.x;
    if (s >= SUP) return;
    float cnt = fmaxf(accum[35 * SUP + s], 1.0f);
    float rc = 1.0f / cnt;
    float col[64];
#pragma unroll
    for (int c = 0; c < 32; ++c) col[c] = accum[c * SUP + s] * rc;
    float vs = 0.f;
#pragma unroll
    for (int c = 0; c < 32; ++c) {
        float v = vit[s * 32 + c];
        col[32 + c] = v;
        vs += v * v;
    }
    float vinv = 1.0f / fmaxf(sqrtf(vs), 1e-12f);
#pragma unroll
    for (int c = 0; c < 32; ++c) col[32 + c] *= vinv;
    float ssq = 0.f;
#pragma unroll
    for (int c = 0; c < 64; ++c) ssq += col[c] * col[c];
    float ainv = 1.0f / fmaxf(sqrtf(ssq), 1e-12f);
#pragma unroll
    for (int c = 0; c < 64; ++c) allF_out[c * SUP + s] = col[c] * ainv;
#pragma unroll
    for (int c = 0; c < 3; ++c) xf_out[c * SUP + s] = accum[(32 + c) * SUP + s] * rc;
}

// ---------------------------------------------------------------------------
// K4: head. conv1d(64->1, k=3, pad=1) over 2048 positions, batchnorm (batch
// stats), sigmoid, global-average-pool. Single block, 512 threads x 4 pos.
// out[0..2047] = result, out[2048] = gap.
// ---------------------------------------------------------------------------
__global__ __launch_bounds__(512) void k_head(const float* __restrict__ allF,
                                              const float* __restrict__ w,
                                              const float* __restrict__ b,
                                              const float* __restrict__ gamma,
                                              const float* __restrict__ beta,
                                              float* __restrict__ out) {
    __shared__ float sw[192];
    __shared__ float red[8];
    __shared__ float bc[2];
    int tid = threadIdx.x;
    for (int i = tid; i < 192; i += 512) sw[i] = w[i];
    __syncthreads();

    float zs[4];
#pragma unroll
    for (int j = 0; j < 4; ++j) {
        int p = j * 512 + tid;
        float acc = b[0];
        for (int c = 0; c < 64; ++c) {
            const float* col = allF + c * SUP + p;
            float am = (p > 0) ? col[-1] : 0.f;
            float a0 = col[0];
            float ap = (p < SUP - 1) ? col[1] : 0.f;
            acc += sw[c * 3] * am + sw[c * 3 + 1] * a0 + sw[c * 3 + 2] * ap;
        }
        zs[j] = acc;
    }

    int lane = tid & 63, wid = tid >> 6;

    // mean
    float s1 = zs[0] + zs[1] + zs[2] + zs[3];
#pragma unroll
    for (int o = 32; o > 0; o >>= 1) s1 += __shfl_down(s1, o);
    if (lane == 0) red[wid] = s1;
    __syncthreads();
    if (tid == 0) {
        float t = 0.f;
        for (int i = 0; i < 8; ++i) t += red[i];
        bc[0] = t / (float)SUP;
    }
    __syncthreads();
    float mu = bc[0];

    // var (two-pass)
    float s2 = 0.f;
#pragma unroll
    for (int j = 0; j < 4; ++j) { float d = zs[j] - mu; s2 += d * d; }
#pragma unroll
    for (int o = 32; o > 0; o >>= 1) s2 += __shfl_down(s2, o);
    __syncthreads();
    if (lane == 0) red[wid] = s2;
    __syncthreads();
    if (tid == 0) {
        float t = 0.f;
        for (int i = 0; i < 8; ++i) t += red[i];
        bc[1] = t / (float)SUP;
    }
    __syncthreads();
    float var = bc[1];

    float invstd = rsqrtf(var + 1e-5f);
    float gm = gamma[0], bt = beta[0];
    float gsum = 0.f;
#pragma unroll
    for (int j = 0; j < 4; ++j) {
        int p = j * 512 + tid;
        float zn = gm * (zs[j] - mu) * invstd + bt;
        float r = 1.0f / (1.0f + expf(-zn));
        out[p] = r;
        gsum += r;
    }
#pragma unroll
    for (int o = 32; o > 0; o >>= 1) gsum += __shfl_down(gsum, o);
    __syncthreads();
    if (lane == 0) red[wid] = gsum;
    __syncthreads();
    if (tid == 0) {
        float t = 0.f;
        for (int i = 0; i < 8; ++i) t += red[i];
        out[SUP] = t / (float)SUP;
    }
}

extern "C" void kernel_launch(void* const* d_in, const int* in_sizes, int n_in,
                              void* d_out, int out_size, void* d_ws, size_t ws_size,
                              hipStream_t stream) {
    const float* x     = (const float*)d_in[0];
    const float* conv  = (const float*)d_in[1];
    const float* vit   = (const float*)d_in[2];
    const int*   ids   = (const int*)d_in[3];
    const float* w     = (const float*)d_in[4];
    const float* b     = (const float*)d_in[5];
    const float* gamma = (const float*)d_in[6];
    const float* beta  = (const float*)d_in[7];
    float* out = (float*)d_out;

    int npix = in_sizes[3];  // B*H*W = 1048576

    float* inv = (float*)d_ws;                // npix floats
    float* accum = inv + npix;                // 36*SUP floats

    hipMemsetAsync(accum, 0, 36 * SUP * sizeof(float), stream);

    k_invnorm<<<(npix + 255) / 256, 256, 0, stream>>>(conv, inv, npix);

    dim3 g2(64, 5);
    k_segacc<<<g2, 512, 0, stream>>>(conv, x, ids, inv, accum, npix);

    float* allF = out + SUP + 1;              // out offset 2049
    float* xf = allF + 64 * SUP;              // out offset 133121
    k_final<<<(SUP + 255) / 256, 256, 0, stream>>>(accum, vit, allF, xf);

    k_head<<<1, 512, 0, stream>>>(allF, w, b, gamma, beta, out);
}

// Round 2
// 289.820 us; speedup vs baseline: 1.1385x; 1.1385x over previous
//
#include <hip/hip_runtime.h>
#include <hip/hip_bf16.h>

#define SUP 2048
#define NXB 128   // x-blocks per group in k_segacc

// ---------------------------------------------------------------------------
// K1: per-pixel inverse L2 norm over the 32 conv channels, 4 pixels/thread.
// conv layout [C=32][npix].
// ---------------------------------------------------------------------------
__global__ __launch_bounds__(256) void k_invnorm(const float* __restrict__ conv,
                                                 float* __restrict__ inv,
                                                 int npix) {
    int t = blockIdx.x * blockDim.x + threadIdx.x;
    int p = t * 4;
    if (p + 3 < npix) {
        float4 s = {0.f, 0.f, 0.f, 0.f};
#pragma unroll
        for (int c = 0; c < 32; ++c) {
            float4 v = *(const float4*)(conv + (size_t)c * npix + p);
            s.x += v.x * v.x; s.y += v.y * v.y; s.z += v.z * v.z; s.w += v.w * v.w;
        }
        float4 r;
        r.x = 1.0f / fmaxf(sqrtf(s.x), 1e-12f);
        r.y = 1.0f / fmaxf(sqrtf(s.y), 1e-12f);
        r.z = 1.0f / fmaxf(sqrtf(s.z), 1e-12f);
        r.w = 1.0f / fmaxf(sqrtf(s.w), 1e-12f);
        *(float4*)(inv + p) = r;
    } else {
        for (; p < npix; ++p) {
            float s = 0.f;
#pragma unroll
            for (int c = 0; c < 32; ++c) {
                float v = conv[(size_t)c * npix + p];
                s += v * v;
            }
            inv[p] = 1.0f / fmaxf(sqrtf(s), 1e-12f);
        }
    }
}

// ---------------------------------------------------------------------------
// K2: segment accumulation with LDS privatization, 4-pixel vectorized.
// gridDim.y = 5 groups: g=0..3 -> conv channels [g*8, g*8+8) (normalized);
//                       g=4    -> x channels (3) + count.
// Flush: per-block partials (pbuf != nullptr) or global atomics (fallback).
// pbuf layout: [NXB][36][SUP].
// ---------------------------------------------------------------------------
__global__ __launch_bounds__(512) void k_segacc(const float* __restrict__ conv,
                                                const float* __restrict__ x,
                                                const int* __restrict__ ids,
                                                const float* __restrict__ inv,
                                                float* __restrict__ accum,
                                                float* __restrict__ pbuf,
                                                int npix) {
    __shared__ float sacc[8 * SUP];  // 64 KiB
    int g = blockIdx.y;
    int nsl = (g < 4) ? 8 * SUP : 4 * SUP;
    for (int i = threadIdx.x; i < nsl; i += blockDim.x) sacc[i] = 0.f;
    __syncthreads();

    int per = ((npix + (int)gridDim.x - 1) / (int)gridDim.x + 3) & ~3;  // mult of 4
    int start = blockIdx.x * per;
    int end = min(start + per, npix);
    int nvec = (end > start) ? ((end - start) & ~3) : 0;
    int vend = start + nvec;

    if (g < 4) {
        const float* c0 = conv + (size_t)g * 8 * npix;
        for (int p = start + (int)threadIdx.x * 4; p < vend; p += (int)blockDim.x * 4) {
            int4   s4 = *(const int4*)(ids + p);
            float4 w4 = *(const float4*)(inv + p);
#pragma unroll
            for (int c = 0; c < 8; ++c) {
                float4 v = *(const float4*)(c0 + (size_t)c * npix + p);
                unsafeAtomicAdd(&sacc[c * SUP + s4.x], v.x * w4.x);
                unsafeAtomicAdd(&sacc[c * SUP + s4.y], v.y * w4.y);
                unsafeAtomicAdd(&sacc[c * SUP + s4.z], v.z * w4.z);
                unsafeAtomicAdd(&sacc[c * SUP + s4.w], v.w * w4.w);
            }
        }
        // scalar tail
        for (int p = vend + (int)threadIdx.x; p < end; p += (int)blockDim.x) {
            int s = ids[p];
            float w = inv[p];
#pragma unroll
            for (int c = 0; c < 8; ++c)
                unsafeAtomicAdd(&sacc[c * SUP + s], c0[(size_t)c * npix + p] * w);
        }
    } else {
        for (int p = start + (int)threadIdx.x * 4; p < vend; p += (int)blockDim.x * 4) {
            int4   s4 = *(const int4*)(ids + p);
            float4 a = *(const float4*)(x + p);
            float4 b = *(const float4*)(x + (size_t)npix + p);
            float4 c = *(const float4*)(x + (size_t)2 * npix + p);
            unsafeAtomicAdd(&sacc[0 * SUP + s4.x], a.x);
            unsafeAtomicAdd(&sacc[0 * SUP + s4.y], a.y);
            unsafeAtomicAdd(&sacc[0 * SUP + s4.z], a.z);
            unsafeAtomicAdd(&sacc[0 * SUP + s4.w], a.w);
            unsafeAtomicAdd(&sacc[1 * SUP + s4.x], b.x);
            unsafeAtomicAdd(&sacc[1 * SUP + s4.y], b.y);
            unsafeAtomicAdd(&sacc[1 * SUP + s4.z], b.z);
            unsafeAtomicAdd(&sacc[1 * SUP + s4.w], b.w);
            unsafeAtomicAdd(&sacc[2 * SUP + s4.x], c.x);
            unsafeAtomicAdd(&sacc[2 * SUP + s4.y], c.y);
            unsafeAtomicAdd(&sacc[2 * SUP + s4.z], c.z);
            unsafeAtomicAdd(&sacc[2 * SUP + s4.w], c.w);
            unsafeAtomicAdd(&sacc[3 * SUP + s4.x], 1.0f);
            unsafeAtomicAdd(&sacc[3 * SUP + s4.y], 1.0f);
            unsafeAtomicAdd(&sacc[3 * SUP + s4.z], 1.0f);
            unsafeAtomicAdd(&sacc[3 * SUP + s4.w], 1.0f);
        }
        for (int p = vend + (int)threadIdx.x; p < end; p += (int)blockDim.x) {
            int s = ids[p];
            unsafeAtomicAdd(&sacc[0 * SUP + s], x[p]);
            unsafeAtomicAdd(&sacc[1 * SUP + s], x[(size_t)npix + p]);
            unsafeAtomicAdd(&sacc[2 * SUP + s], x[(size_t)2 * npix + p]);
            unsafeAtomicAdd(&sacc[3 * SUP + s], 1.0f);
        }
    }
    __syncthreads();

    int base = (g < 4) ? g * 8 * SUP : 32 * SUP;
    if (pbuf) {
        float* dst = pbuf + (size_t)blockIdx.x * 36 * SUP + base;
        for (int i = threadIdx.x; i < nsl; i += blockDim.x) dst[i] = sacc[i];
    } else {
        for (int i = threadIdx.x; i < nsl; i += blockDim.x)
            unsafeAtomicAdd(&accum[base + i], sacc[i]);
    }
}

// ---------------------------------------------------------------------------
// K2b: reduce per-block partials -> accum[36][SUP].
// ---------------------------------------------------------------------------
__global__ __launch_bounds__(256) void k_reduce(const float* __restrict__ pbuf,
                                                float* __restrict__ accum) {
    int j = blockIdx.x * blockDim.x + threadIdx.x;
    if (j >= 36 * SUP) return;
    float s = 0.f;
#pragma unroll 4
    for (int b = 0; b < NXB; ++b) s += pbuf[(size_t)b * 36 * SUP + j];
    accum[j] = s;
}

// ---------------------------------------------------------------------------
// K3: per-segment finalize -> all_F (l2norm of concat) and X_F outputs.
// ---------------------------------------------------------------------------
__global__ __launch_bounds__(256) void k_final(const float* __restrict__ accum,
                                               const float* __restrict__ vit,
                                               float* __restrict__ allF_out,
                                               float* __restrict__ xf_out) {
    int s = blockIdx.x * blockDim.x + threadIdx.x;
    if (s >= SUP) return;
    float cnt = fmaxf(accum[35 * SUP + s], 1.0f);
    float rc = 1.0f / cnt;
    float col[64];
#pragma unroll
    for (int c = 0; c < 32; ++c) col[c] = accum[c * SUP + s] * rc;
    float vs = 0.f;
#pragma unroll
    for (int c = 0; c < 32; ++c) {
        float v = vit[s * 32 + c];
        col[32 + c] = v;
        vs += v * v;
    }
    float vinv = 1.0f / fmaxf(sqrtf(vs), 1e-12f);
#pragma unroll
    for (int c = 0; c < 32; ++c) col[32 + c] *= vinv;
    float ssq = 0.f;
#pragma unroll
    for (int c = 0; c < 64; ++c) ssq += col[c] * col[c];
    float ainv = 1.0f / fmaxf(sqrtf(ssq), 1e-12f);
#pragma unroll
    for (int c = 0; c < 64; ++c) allF_out[c * SUP + s] = col[c] * ainv;
#pragma unroll
    for (int c = 0; c < 3; ++c) xf_out[c * SUP + s] = accum[(32 + c) * SUP + s] * rc;
}

// ---------------------------------------------------------------------------
// K4: head. conv1d(64->1,k=3,pad=1), batchnorm (batch stats), sigmoid, gap.
// Single block, 512 threads x 4 positions.
// ---------------------------------------------------------------------------
__global__ __launch_bounds__(512) void k_head(const float* __restrict__ allF,
                                              const float* __restrict__ w,
                                              const float* __restrict__ b,
                                              const float* __restrict__ gamma,
                                              const float* __restrict__ beta,
                                              float* __restrict__ out) {
    __shared__ float sw[192];
    __shared__ float red[8];
    __shared__ float bc[2];
    int tid = threadIdx.x;
    for (int i = tid; i < 192; i += 512) sw[i] = w[i];
    __syncthreads();

    float zs[4];
#pragma unroll
    for (int j = 0; j < 4; ++j) {
        int p = j * 512 + tid;
        float acc = b[0];
        for (int c = 0; c < 64; ++c) {
            const float* col = allF + c * SUP + p;
            float am = (p > 0) ? col[-1] : 0.f;
            float a0 = col[0];
            float ap = (p < SUP - 1) ? col[1] : 0.f;
            acc += sw[c * 3] * am + sw[c * 3 + 1] * a0 + sw[c * 3 + 2] * ap;
        }
        zs[j] = acc;
    }

    int lane = tid & 63, wid = tid >> 6;

    float s1 = zs[0] + zs[1] + zs[2] + zs[3];
#pragma unroll
    for (int o = 32; o > 0; o >>= 1) s1 += __shfl_down(s1, o);
    if (lane == 0) red[wid] = s1;
    __syncthreads();
    if (tid == 0) {
        float t = 0.f;
        for (int i = 0; i < 8; ++i) t += red[i];
        bc[0] = t / (float)SUP;
    }
    __syncthreads();
    float mu = bc[0];

    float s2 = 0.f;
#pragma unroll
    for (int j = 0; j < 4; ++j) { float d = zs[j] - mu; s2 += d * d; }
#pragma unroll
    for (int o = 32; o > 0; o >>= 1) s2 += __shfl_down(s2, o);
    __syncthreads();
    if (lane == 0) red[wid] = s2;
    __syncthreads();
    if (tid == 0) {
        float t = 0.f;
        for (int i = 0; i < 8; ++i) t += red[i];
        bc[1] = t / (float)SUP;
    }
    __syncthreads();
    float var = bc[1];

    float invstd = rsqrtf(var + 1e-5f);
    float gm = gamma[0], bt = beta[0];
    float gsum = 0.f;
#pragma unroll
    for (int j = 0; j < 4; ++j) {
        int p = j * 512 + tid;
        float zn = gm * (zs[j] - mu) * invstd + bt;
        float r = 1.0f / (1.0f + expf(-zn));
        out[p] = r;
        gsum += r;
    }
#pragma unroll
    for (int o = 32; o > 0; o >>= 1) gsum += __shfl_down(gsum, o);
    __syncthreads();
    if (lane == 0) red[wid] = gsum;
    __syncthreads();
    if (tid == 0) {
        float t = 0.f;
        for (int i = 0; i < 8; ++i) t += red[i];
        out[SUP] = t / (float)SUP;
    }
}

extern "C" void kernel_launch(void* const* d_in, const int* in_sizes, int n_in,
                              void* d_out, int out_size, void* d_ws, size_t ws_size,
                              hipStream_t stream) {
    const float* x     = (const float*)d_in[0];
    const float* conv  = (const float*)d_in[1];
    const float* vit   = (const float*)d_in[2];
    const int*   ids   = (const int*)d_in[3];
    const float* w     = (const float*)d_in[4];
    const float* b     = (const float*)d_in[5];
    const float* gamma = (const float*)d_in[6];
    const float* beta  = (const float*)d_in[7];
    float* out = (float*)d_out;

    int npix = in_sizes[3];  // B*H*W = 1048576

    float* inv = (float*)d_ws;                 // npix floats
    float* accum = inv + npix;                 // 36*SUP floats
    float* pbuf = accum + 36 * SUP;            // NXB*36*SUP floats (if it fits)

    size_t need = ((size_t)npix + 36 * SUP + (size_t)NXB * 36 * SUP) * sizeof(float);
    bool useP = ws_size >= need;

    if (!useP) hipMemsetAsync(accum, 0, 36 * SUP * sizeof(float), stream);

    int nquad = (npix + 3) / 4;
    k_invnorm<<<(nquad + 255) / 256, 256, 0, stream>>>(conv, inv, npix);

    dim3 g2(NXB, 5);
    k_segacc<<<g2, 512, 0, stream>>>(conv, x, ids, inv, accum,
                                     useP ? pbuf : (float*)nullptr, npix);
    if (useP) {
        k_reduce<<<(36 * SUP + 255) / 256, 256, 0, stream>>>(pbuf, accum);
    }

    float* allF = out + SUP + 1;               // out offset 2049
    float* xf = allF + 64 * SUP;               // out offset 133121
    k_final<<<(SUP + 255) / 256, 256, 0, stream>>>(accum, vit, allF, xf);

    k_head<<<1, 512, 0, stream>>>(allF, w, b, gamma, beta, out);
}

// Round 3
// 104.515 us; speedup vs baseline: 3.1571x; 2.7730x over previous
//
#include <hip/hip_runtime.h>
#include <hip/hip_bf16.h>

#define SUP 2048
#define NXB 128   // x-blocks per group in k_segacc
#define NG  6     // y-groups; each owns 6 accumulator rows (36 = 6*6)

#define S_CONV 2097152.0f        // 2^21 : |normalized conv| <= 1
#define S_X    131072.0f         // 2^17 : x ~ N(0,1)
#define IS_CONV (1.0f/2097152.0f)
#define IS_X    (1.0f/131072.0f)

// ---------------------------------------------------------------------------
// K1: per-pixel inverse L2 norm over the 32 conv channels, 4 pixels/thread.
// conv layout [C=32][npix].
// ---------------------------------------------------------------------------
__global__ __launch_bounds__(256) void k_invnorm(const float* __restrict__ conv,
                                                 float* __restrict__ inv,
                                                 int npix) {
    int t = blockIdx.x * blockDim.x + threadIdx.x;
    int p = t * 4;
    if (p + 3 < npix) {
        float4 s = {0.f, 0.f, 0.f, 0.f};
#pragma unroll
        for (int c = 0; c < 32; ++c) {
            float4 v = *(const float4*)(conv + (size_t)c * npix + p);
            s.x += v.x * v.x; s.y += v.y * v.y; s.z += v.z * v.z; s.w += v.w * v.w;
        }
        float4 r;
        r.x = 1.0f / fmaxf(sqrtf(s.x), 1e-12f);
        r.y = 1.0f / fmaxf(sqrtf(s.y), 1e-12f);
        r.z = 1.0f / fmaxf(sqrtf(s.z), 1e-12f);
        r.w = 1.0f / fmaxf(sqrtf(s.w), 1e-12f);
        *(float4*)(inv + p) = r;
    } else {
        for (; p < npix; ++p) {
            float s = 0.f;
#pragma unroll
            for (int c = 0; c < 32; ++c) {
                float v = conv[(size_t)c * npix + p];
                s += v * v;
            }
            inv[p] = 1.0f / fmaxf(sqrtf(s), 1e-12f);
        }
    }
}

// ---------------------------------------------------------------------------
// K2: segment accumulation, LDS-privatized with NATIVE integer atomics
// (ds_add_u32) on fixed-point values. 48 KiB LDS -> 3 blocks/CU.
// groups g=0..4: conv channels [6g, 6g+6) normalized by inv.
// group  g=5   : slots {conv30, conv31, x0, x1, x2, count}.
// Accum row index = g*6 + slot (rows 0..31 conv, 32..34 x, 35 count).
// Flush: per-block float partials pbuf[NXB][36][SUP], or global atomics.
// ---------------------------------------------------------------------------
__global__ __launch_bounds__(512) void k_segacc(const float* __restrict__ conv,
                                                const float* __restrict__ x,
                                                const int* __restrict__ ids,
                                                const float* __restrict__ inv,
                                                float* __restrict__ accum,
                                                float* __restrict__ pbuf,
                                                int npix) {
    __shared__ int sacc[6 * SUP];  // 48 KiB
    int g = blockIdx.y;
    for (int i = threadIdx.x; i < 6 * SUP; i += blockDim.x) sacc[i] = 0;
    __syncthreads();

    int per = ((npix + (int)gridDim.x - 1) / (int)gridDim.x + 3) & ~3;  // mult of 4
    int start = blockIdx.x * per;
    int end = min(start + per, npix);
    int nvec = (end > start) ? ((end - start) & ~3) : 0;
    int vend = start + nvec;

    if (g < 5) {
        const float* c0 = conv + (size_t)g * 6 * npix;
        for (int p = start + (int)threadIdx.x * 4; p < vend; p += (int)blockDim.x * 4) {
            int4   s4 = *(const int4*)(ids + p);
            float4 w4 = *(const float4*)(inv + p);
#pragma unroll
            for (int c = 0; c < 6; ++c) {
                float4 v = *(const float4*)(c0 + (size_t)c * npix + p);
                atomicAdd(&sacc[c * SUP + s4.x], __float2int_rn(v.x * w4.x * S_CONV));
                atomicAdd(&sacc[c * SUP + s4.y], __float2int_rn(v.y * w4.y * S_CONV));
                atomicAdd(&sacc[c * SUP + s4.z], __float2int_rn(v.z * w4.z * S_CONV));
                atomicAdd(&sacc[c * SUP + s4.w], __float2int_rn(v.w * w4.w * S_CONV));
            }
        }
        for (int p = vend + (int)threadIdx.x; p < end; p += (int)blockDim.x) {
            int s = ids[p];
            float w = inv[p];
#pragma unroll
            for (int c = 0; c < 6; ++c)
                atomicAdd(&sacc[c * SUP + s],
                          __float2int_rn(c0[(size_t)c * npix + p] * w * S_CONV));
        }
    } else {
        const float* c30 = conv + (size_t)30 * npix;
        const float* c31 = conv + (size_t)31 * npix;
        for (int p = start + (int)threadIdx.x * 4; p < vend; p += (int)blockDim.x * 4) {
            int4   s4 = *(const int4*)(ids + p);
            float4 w4 = *(const float4*)(inv + p);
            float4 va = *(const float4*)(c30 + p);
            float4 vb = *(const float4*)(c31 + p);
            float4 a = *(const float4*)(x + p);
            float4 b = *(const float4*)(x + (size_t)npix + p);
            float4 c = *(const float4*)(x + (size_t)2 * npix + p);
            atomicAdd(&sacc[0 * SUP + s4.x], __float2int_rn(va.x * w4.x * S_CONV));
            atomicAdd(&sacc[0 * SUP + s4.y], __float2int_rn(va.y * w4.y * S_CONV));
            atomicAdd(&sacc[0 * SUP + s4.z], __float2int_rn(va.z * w4.z * S_CONV));
            atomicAdd(&sacc[0 * SUP + s4.w], __float2int_rn(va.w * w4.w * S_CONV));
            atomicAdd(&sacc[1 * SUP + s4.x], __float2int_rn(vb.x * w4.x * S_CONV));
            atomicAdd(&sacc[1 * SUP + s4.y], __float2int_rn(vb.y * w4.y * S_CONV));
            atomicAdd(&sacc[1 * SUP + s4.z], __float2int_rn(vb.z * w4.z * S_CONV));
            atomicAdd(&sacc[1 * SUP + s4.w], __float2int_rn(vb.w * w4.w * S_CONV));
            atomicAdd(&sacc[2 * SUP + s4.x], __float2int_rn(a.x * S_X));
            atomicAdd(&sacc[2 * SUP + s4.y], __float2int_rn(a.y * S_X));
            atomicAdd(&sacc[2 * SUP + s4.z], __float2int_rn(a.z * S_X));
            atomicAdd(&sacc[2 * SUP + s4.w], __float2int_rn(a.w * S_X));
            atomicAdd(&sacc[3 * SUP + s4.x], __float2int_rn(b.x * S_X));
            atomicAdd(&sacc[3 * SUP + s4.y], __float2int_rn(b.y * S_X));
            atomicAdd(&sacc[3 * SUP + s4.z], __float2int_rn(b.z * S_X));
            atomicAdd(&sacc[3 * SUP + s4.w], __float2int_rn(b.w * S_X));
            atomicAdd(&sacc[4 * SUP + s4.x], __float2int_rn(c.x * S_X));
            atomicAdd(&sacc[4 * SUP + s4.y], __float2int_rn(c.y * S_X));
            atomicAdd(&sacc[4 * SUP + s4.z], __float2int_rn(c.z * S_X));
            atomicAdd(&sacc[4 * SUP + s4.w], __float2int_rn(c.w * S_X));
            atomicAdd(&sacc[5 * SUP + s4.x], 1);
            atomicAdd(&sacc[5 * SUP + s4.y], 1);
            atomicAdd(&sacc[5 * SUP + s4.z], 1);
            atomicAdd(&sacc[5 * SUP + s4.w], 1);
        }
        for (int p = vend + (int)threadIdx.x; p < end; p += (int)blockDim.x) {
            int s = ids[p];
            float w = inv[p];
            atomicAdd(&sacc[0 * SUP + s], __float2int_rn(c30[p] * w * S_CONV));
            atomicAdd(&sacc[1 * SUP + s], __float2int_rn(c31[p] * w * S_CONV));
            atomicAdd(&sacc[2 * SUP + s], __float2int_rn(x[p] * S_X));
            atomicAdd(&sacc[3 * SUP + s], __float2int_rn(x[(size_t)npix + p] * S_X));
            atomicAdd(&sacc[4 * SUP + s], __float2int_rn(x[(size_t)2 * npix + p] * S_X));
            atomicAdd(&sacc[5 * SUP + s], 1);
        }
    }
    __syncthreads();

    int base = g * 6 * SUP;
    if (pbuf) {
        float* dst = pbuf + (size_t)blockIdx.x * 36 * SUP + base;
        for (int i = threadIdx.x; i < 6 * SUP; i += blockDim.x) {
            int slot = i >> 11;
            float sc = (g < 5 || slot < 2) ? IS_CONV : (slot < 5 ? IS_X : 1.0f);
            dst[i] = (float)sacc[i] * sc;
        }
    } else {
        for (int i = threadIdx.x; i < 6 * SUP; i += blockDim.x) {
            int slot = i >> 11;
            float sc = (g < 5 || slot < 2) ? IS_CONV : (slot < 5 ? IS_X : 1.0f);
            unsafeAtomicAdd(&accum[base + i], (float)sacc[i] * sc);
        }
    }
}

// ---------------------------------------------------------------------------
// K2b: reduce per-block partials -> accum[36][SUP].
// ---------------------------------------------------------------------------
__global__ __launch_bounds__(256) void k_reduce(const float* __restrict__ pbuf,
                                                float* __restrict__ accum) {
    int j = blockIdx.x * blockDim.x + threadIdx.x;
    if (j >= 36 * SUP) return;
    float s = 0.f;
#pragma unroll 4
    for (int b = 0; b < NXB; ++b) s += pbuf[(size_t)b * 36 * SUP + j];
    accum[j] = s;
}

// ---------------------------------------------------------------------------
// K3: per-segment finalize -> all_F (l2norm of concat) and X_F outputs.
// ---------------------------------------------------------------------------
__global__ __launch_bounds__(256) void k_final(const float* __restrict__ accum,
                                               const float* __restrict__ vit,
                                               float* __restrict__ allF_out,
                                               float* __restrict__ xf_out) {
    int s = blockIdx.x * blockDim.x + threadIdx.x;
    if (s >= SUP) return;
    float cnt = fmaxf(accum[35 * SUP + s], 1.0f);
    float rc = 1.0f / cnt;
    float col[64];
#pragma unroll
    for (int c = 0; c < 32; ++c) col[c] = accum[c * SUP + s] * rc;
    float vs = 0.f;
#pragma unroll
    for (int c = 0; c < 32; ++c) {
        float v = vit[s * 32 + c];
        col[32 + c] = v;
        vs += v * v;
    }
    float vinv = 1.0f / fmaxf(sqrtf(vs), 1e-12f);
#pragma unroll
    for (int c = 0; c < 32; ++c) col[32 + c] *= vinv;
    float ssq = 0.f;
#pragma unroll
    for (int c = 0; c < 64; ++c) ssq += col[c] * col[c];
    float ainv = 1.0f / fmaxf(sqrtf(ssq), 1e-12f);
#pragma unroll
    for (int c = 0; c < 64; ++c) allF_out[c * SUP + s] = col[c] * ainv;
#pragma unroll
    for (int c = 0; c < 3; ++c) xf_out[c * SUP + s] = accum[(32 + c) * SUP + s] * rc;
}

// ---------------------------------------------------------------------------
// K4: head. conv1d(64->1,k=3,pad=1), batchnorm (batch stats), sigmoid, gap.
// ---------------------------------------------------------------------------
__global__ __launch_bounds__(512) void k_head(const float* __restrict__ allF,
                                              const float* __restrict__ w,
                                              const float* __restrict__ b,
                                              const float* __restrict__ gamma,
                                              const float* __restrict__ beta,
                                              float* __restrict__ out) {
    __shared__ float sw[192];
    __shared__ float red[8];
    __shared__ float bc[2];
    int tid = threadIdx.x;
    for (int i = tid; i < 192; i += 512) sw[i] = w[i];
    __syncthreads();

    float zs[4];
#pragma unroll
    for (int j = 0; j < 4; ++j) {
        int p = j * 512 + tid;
        float acc = b[0];
        for (int c = 0; c < 64; ++c) {
            const float* col = allF + c * SUP + p;
            float am = (p > 0) ? col[-1] : 0.f;
            float a0 = col[0];
            float ap = (p < SUP - 1) ? col[1] : 0.f;
            acc += sw[c * 3] * am + sw[c * 3 + 1] * a0 + sw[c * 3 + 2] * ap;
        }
        zs[j] = acc;
    }

    int lane = tid & 63, wid = tid >> 6;

    float s1 = zs[0] + zs[1] + zs[2] + zs[3];
#pragma unroll
    for (int o = 32; o > 0; o >>= 1) s1 += __shfl_down(s1, o);
    if (lane == 0) red[wid] = s1;
    __syncthreads();
    if (tid == 0) {
        float t = 0.f;
        for (int i = 0; i < 8; ++i) t += red[i];
        bc[0] = t / (float)SUP;
    }
    __syncthreads();
    float mu = bc[0];

    float s2 = 0.f;
#pragma unroll
    for (int j = 0; j < 4; ++j) { float d = zs[j] - mu; s2 += d * d; }
#pragma unroll
    for (int o = 32; o > 0; o >>= 1) s2 += __shfl_down(s2, o);
    __syncthreads();
    if (lane == 0) red[wid] = s2;
    __syncthreads();
    if (tid == 0) {
        float t = 0.f;
        for (int i = 0; i < 8; ++i) t += red[i];
        bc[1] = t / (float)SUP;
    }
    __syncthreads();
    float var = bc[1];

    float invstd = rsqrtf(var + 1e-5f);
    float gm = gamma[0], bt = beta[0];
    float gsum = 0.f;
#pragma unroll
    for (int j = 0; j < 4; ++j) {
        int p = j * 512 + tid;
        float zn = gm * (zs[j] - mu) * invstd + bt;
        float r = 1.0f / (1.0f + expf(-zn));
        out[p] = r;
        gsum += r;
    }
#pragma unroll
    for (int o = 32; o > 0; o >>= 1) gsum += __shfl_down(gsum, o);
    __syncthreads();
    if (lane == 0) red[wid] = gsum;
    __syncthreads();
    if (tid == 0) {
        float t = 0.f;
        for (int i = 0; i < 8; ++i) t += red[i];
        out[SUP] = t / (float)SUP;
    }
}

extern "C" void kernel_launch(void* const* d_in, const int* in_sizes, int n_in,
                              void* d_out, int out_size, void* d_ws, size_t ws_size,
                              hipStream_t stream) {
    const float* x     = (const float*)d_in[0];
    const float* conv  = (const float*)d_in[1];
    const float* vit   = (const float*)d_in[2];
    const int*   ids   = (const int*)d_in[3];
    const float* w     = (const float*)d_in[4];
    const float* b     = (const float*)d_in[5];
    const float* gamma = (const float*)d_in[6];
    const float* beta  = (const float*)d_in[7];
    float* out = (float*)d_out;

    int npix = in_sizes[3];  // B*H*W = 1048576

    float* inv = (float*)d_ws;                 // npix floats
    float* accum = inv + npix;                 // 36*SUP floats
    float* pbuf = accum + 36 * SUP;            // NXB*36*SUP floats (if it fits)

    size_t need = ((size_t)npix + 36 * SUP + (size_t)NXB * 36 * SUP) * sizeof(float);
    bool useP = ws_size >= need;

    if (!useP) hipMemsetAsync(accum, 0, 36 * SUP * sizeof(float), stream);

    int nquad = (npix + 3) / 4;
    k_invnorm<<<(nquad + 255) / 256, 256, 0, stream>>>(conv, inv, npix);

    dim3 g2(NXB, NG);
    k_segacc<<<g2, 512, 0, stream>>>(conv, x, ids, inv, accum,
                                     useP ? pbuf : (float*)nullptr, npix);
    if (useP) {
        k_reduce<<<(36 * SUP + 255) / 256, 256, 0, stream>>>(pbuf, accum);
    }

    float* allF = out + SUP + 1;               // out offset 2049
    float* xf = allF + 64 * SUP;               // out offset 133121
    k_final<<<(SUP + 255) / 256, 256, 0, stream>>>(accum, vit, allF, xf);

    k_head<<<1, 512, 0, stream>>>(allF, w, b, gamma, beta, out);
}

// Round 4
// 80.682 us; speedup vs baseline: 4.0897x; 1.2954x over previous
//
#include <hip/hip_runtime.h>
#include <hip/hip_bf16.h>
#include <hip/hip_fp16.h>

#define SUP 2048
#define NXB 128   // x-blocks per group in k_segacc
#define NG  6     // y-groups; each owns 6 accumulator rows (36 = 6*6)

#define S_CONV 2097152.0f        // 2^21 : |normalized conv| <= 1
#define S_X    131072.0f         // 2^17 : x ~ N(0,1)
#define IS_CONV (1.0f/2097152.0f)
#define IS_X    (1.0f/131072.0f)

// ---------------------------------------------------------------------------
// K1: per-pixel inverse L2 norm over the 32 conv channels, 4 pixels/thread.
// conv layout [C=32][npix].
// ---------------------------------------------------------------------------
__global__ __launch_bounds__(256) void k_invnorm(const float* __restrict__ conv,
                                                 float* __restrict__ inv,
                                                 int npix) {
    int t = blockIdx.x * blockDim.x + threadIdx.x;
    int p = t * 4;
    if (p + 3 < npix) {
        float4 s = {0.f, 0.f, 0.f, 0.f};
#pragma unroll
        for (int c = 0; c < 32; ++c) {
            float4 v = *(const float4*)(conv + (size_t)c * npix + p);
            s.x += v.x * v.x; s.y += v.y * v.y; s.z += v.z * v.z; s.w += v.w * v.w;
        }
        float4 r;
        r.x = 1.0f / fmaxf(sqrtf(s.x), 1e-12f);
        r.y = 1.0f / fmaxf(sqrtf(s.y), 1e-12f);
        r.z = 1.0f / fmaxf(sqrtf(s.z), 1e-12f);
        r.w = 1.0f / fmaxf(sqrtf(s.w), 1e-12f);
        *(float4*)(inv + p) = r;
    } else {
        for (; p < npix; ++p) {
            float s = 0.f;
#pragma unroll
            for (int c = 0; c < 32; ++c) {
                float v = conv[(size_t)c * npix + p];
                s += v * v;
            }
            inv[p] = 1.0f / fmaxf(sqrtf(s), 1e-12f);
        }
    }
}

// ---------------------------------------------------------------------------
// K2: segment accumulation, LDS-privatized with native integer atomics
// (ds_add) on fixed-point values. 48 KiB LDS -> 3 blocks/CU.
// groups g=0..4: conv channels [6g, 6g+6) normalized by inv.
// group  g=5   : slots {conv30, conv31, x0, x1, x2, count}.
// Flush: per-block fp16 partials pbuf[NXB][36][SUP], or global f32 atomics.
// ---------------------------------------------------------------------------
__global__ __launch_bounds__(512) void k_segacc(const float* __restrict__ conv,
                                                const float* __restrict__ x,
                                                const int* __restrict__ ids,
                                                const float* __restrict__ inv,
                                                float* __restrict__ accum,
                                                __half* __restrict__ pbuf,
                                                int npix) {
    __shared__ int sacc[6 * SUP];  // 48 KiB
    int g = blockIdx.y;
    for (int i = threadIdx.x; i < 6 * SUP; i += blockDim.x) sacc[i] = 0;
    __syncthreads();

    int per = ((npix + (int)gridDim.x - 1) / (int)gridDim.x + 3) & ~3;  // mult of 4
    int start = blockIdx.x * per;
    int end = min(start + per, npix);
    int nvec = (end > start) ? ((end - start) & ~3) : 0;
    int vend = start + nvec;

    if (g < 5) {
        const float* c0 = conv + (size_t)g * 6 * npix;
        for (int p = start + (int)threadIdx.x * 4; p < vend; p += (int)blockDim.x * 4) {
            int4   s4 = *(const int4*)(ids + p);
            float4 w4 = *(const float4*)(inv + p);
#pragma unroll
            for (int c = 0; c < 6; ++c) {
                float4 v = *(const float4*)(c0 + (size_t)c * npix + p);
                atomicAdd(&sacc[c * SUP + s4.x], __float2int_rn(v.x * w4.x * S_CONV));
                atomicAdd(&sacc[c * SUP + s4.y], __float2int_rn(v.y * w4.y * S_CONV));
                atomicAdd(&sacc[c * SUP + s4.z], __float2int_rn(v.z * w4.z * S_CONV));
                atomicAdd(&sacc[c * SUP + s4.w], __float2int_rn(v.w * w4.w * S_CONV));
            }
        }
        for (int p = vend + (int)threadIdx.x; p < end; p += (int)blockDim.x) {
            int s = ids[p];
            float w = inv[p];
#pragma unroll
            for (int c = 0; c < 6; ++c)
                atomicAdd(&sacc[c * SUP + s],
                          __float2int_rn(c0[(size_t)c * npix + p] * w * S_CONV));
        }
    } else {
        const float* c30 = conv + (size_t)30 * npix;
        const float* c31 = conv + (size_t)31 * npix;
        for (int p = start + (int)threadIdx.x * 4; p < vend; p += (int)blockDim.x * 4) {
            int4   s4 = *(const int4*)(ids + p);
            float4 w4 = *(const float4*)(inv + p);
            float4 va = *(const float4*)(c30 + p);
            float4 vb = *(const float4*)(c31 + p);
            float4 a = *(const float4*)(x + p);
            float4 b = *(const float4*)(x + (size_t)npix + p);
            float4 c = *(const float4*)(x + (size_t)2 * npix + p);
            atomicAdd(&sacc[0 * SUP + s4.x], __float2int_rn(va.x * w4.x * S_CONV));
            atomicAdd(&sacc[0 * SUP + s4.y], __float2int_rn(va.y * w4.y * S_CONV));
            atomicAdd(&sacc[0 * SUP + s4.z], __float2int_rn(va.z * w4.z * S_CONV));
            atomicAdd(&sacc[0 * SUP + s4.w], __float2int_rn(va.w * w4.w * S_CONV));
            atomicAdd(&sacc[1 * SUP + s4.x], __float2int_rn(vb.x * w4.x * S_CONV));
            atomicAdd(&sacc[1 * SUP + s4.y], __float2int_rn(vb.y * w4.y * S_CONV));
            atomicAdd(&sacc[1 * SUP + s4.z], __float2int_rn(vb.z * w4.z * S_CONV));
            atomicAdd(&sacc[1 * SUP + s4.w], __float2int_rn(vb.w * w4.w * S_CONV));
            atomicAdd(&sacc[2 * SUP + s4.x], __float2int_rn(a.x * S_X));
            atomicAdd(&sacc[2 * SUP + s4.y], __float2int_rn(a.y * S_X));
            atomicAdd(&sacc[2 * SUP + s4.z], __float2int_rn(a.z * S_X));
            atomicAdd(&sacc[2 * SUP + s4.w], __float2int_rn(a.w * S_X));
            atomicAdd(&sacc[3 * SUP + s4.x], __float2int_rn(b.x * S_X));
            atomicAdd(&sacc[3 * SUP + s4.y], __float2int_rn(b.y * S_X));
            atomicAdd(&sacc[3 * SUP + s4.z], __float2int_rn(b.z * S_X));
            atomicAdd(&sacc[3 * SUP + s4.w], __float2int_rn(b.w * S_X));
            atomicAdd(&sacc[4 * SUP + s4.x], __float2int_rn(c.x * S_X));
            atomicAdd(&sacc[4 * SUP + s4.y], __float2int_rn(c.y * S_X));
            atomicAdd(&sacc[4 * SUP + s4.z], __float2int_rn(c.z * S_X));
            atomicAdd(&sacc[4 * SUP + s4.w], __float2int_rn(c.w * S_X));
            atomicAdd(&sacc[5 * SUP + s4.x], 1);
            atomicAdd(&sacc[5 * SUP + s4.y], 1);
            atomicAdd(&sacc[5 * SUP + s4.z], 1);
            atomicAdd(&sacc[5 * SUP + s4.w], 1);
        }
        for (int p = vend + (int)threadIdx.x; p < end; p += (int)blockDim.x) {
            int s = ids[p];
            float w = inv[p];
            atomicAdd(&sacc[0 * SUP + s], __float2int_rn(c30[p] * w * S_CONV));
            atomicAdd(&sacc[1 * SUP + s], __float2int_rn(c31[p] * w * S_CONV));
            atomicAdd(&sacc[2 * SUP + s], __float2int_rn(x[p] * S_X));
            atomicAdd(&sacc[3 * SUP + s], __float2int_rn(x[(size_t)npix + p] * S_X));
            atomicAdd(&sacc[4 * SUP + s], __float2int_rn(x[(size_t)2 * npix + p] * S_X));
            atomicAdd(&sacc[5 * SUP + s], 1);
        }
    }
    __syncthreads();

    int base = g * 6 * SUP;
    if (pbuf) {
        __half* dst = pbuf + (size_t)blockIdx.x * 36 * SUP + base;
        for (int i = threadIdx.x; i < 6 * SUP; i += blockDim.x) {
            int slot = i >> 11;
            float sc = (g < 5 || slot < 2) ? IS_CONV : (slot < 5 ? IS_X : 1.0f);
            dst[i] = __float2half((float)sacc[i] * sc);
        }
    } else {
        for (int i = threadIdx.x; i < 6 * SUP; i += blockDim.x) {
            int slot = i >> 11;
            float sc = (g < 5 || slot < 2) ? IS_CONV : (slot < 5 ? IS_X : 1.0f);
            unsafeAtomicAdd(&accum[base + i], (float)sacc[i] * sc);
        }
    }
}

// ---------------------------------------------------------------------------
// K2b: reduce fp16 per-block partials -> accum[36][SUP]. 8 elements/thread.
// ---------------------------------------------------------------------------
__global__ __launch_bounds__(256) void k_reduce(const __half* __restrict__ pbuf,
                                                float* __restrict__ accum) {
    int j8 = (blockIdx.x * blockDim.x + threadIdx.x) * 8;
    if (j8 >= 36 * SUP) return;
    float s[8];
#pragma unroll
    for (int k = 0; k < 8; ++k) s[k] = 0.f;
    for (int b = 0; b < NXB; ++b) {
        uint4 u = *(const uint4*)(pbuf + (size_t)b * 36 * SUP + j8);
        __half2 h0 = *reinterpret_cast<__half2*>(&u.x);
        __half2 h1 = *reinterpret_cast<__half2*>(&u.y);
        __half2 h2 = *reinterpret_cast<__half2*>(&u.z);
        __half2 h3 = *reinterpret_cast<__half2*>(&u.w);
        float2 f0 = __half22float2(h0), f1 = __half22float2(h1);
        float2 f2 = __half22float2(h2), f3 = __half22float2(h3);
        s[0] += f0.x; s[1] += f0.y; s[2] += f1.x; s[3] += f1.y;
        s[4] += f2.x; s[5] += f2.y; s[6] += f3.x; s[7] += f3.y;
    }
    float4 o0 = {s[0], s[1], s[2], s[3]};
    float4 o1 = {s[4], s[5], s[6], s[7]};
    *(float4*)(accum + j8) = o0;
    *(float4*)(accum + j8 + 4) = o1;
}

// ---------------------------------------------------------------------------
// K3: per-segment finalize + conv1d. Each block owns 256 segments, stages the
// 258-column halo'd all_F tile in LDS (row padded to 65 -> conflict-free),
// writes all_F, X_F, and z = conv1d(all_F) to ws.
// ---------------------------------------------------------------------------
__device__ __forceinline__ void compute_col(const float* __restrict__ accum,
                                            const float* __restrict__ vit,
                                            int g, float* __restrict__ col) {
    if (g < 0 || g >= SUP) {
#pragma unroll
        for (int c = 0; c < 64; ++c) col[c] = 0.f;
        return;
    }
    float cnt = fmaxf(accum[35 * SUP + g], 1.0f);
    float rc = 1.0f / cnt;
#pragma unroll
    for (int c = 0; c < 32; ++c) col[c] = accum[c * SUP + g] * rc;
    float vs = 0.f;
#pragma unroll
    for (int c = 0; c < 32; ++c) {
        float v = vit[g * 32 + c];
        col[32 + c] = v;
        vs += v * v;
    }
    float vinv = 1.0f / fmaxf(sqrtf(vs), 1e-12f);
#pragma unroll
    for (int c = 0; c < 32; ++c) col[32 + c] *= vinv;
    float ssq = 0.f;
#pragma unroll
    for (int c = 0; c < 64; ++c) ssq += col[c] * col[c];
    float ainv = 1.0f / fmaxf(sqrtf(ssq), 1e-12f);
#pragma unroll
    for (int c = 0; c < 64; ++c) col[c] *= ainv;
}

__global__ __launch_bounds__(256) void k_finalconv(const float* __restrict__ accum,
                                                   const float* __restrict__ vit,
                                                   const float* __restrict__ w,
                                                   const float* __restrict__ bias,
                                                   float* __restrict__ allF_out,
                                                   float* __restrict__ xf_out,
                                                   float* __restrict__ z_out) {
    __shared__ float L[258][65];
    __shared__ float sw[192];
    int t = threadIdx.x;
    int b0 = blockIdx.x * 256;
    if (t < 192) sw[t] = w[t];

    float col[64];
    int g = b0 + t;
    compute_col(accum, vit, g, col);
#pragma unroll
    for (int c = 0; c < 64; ++c) L[t + 1][c] = col[c];
#pragma unroll
    for (int c = 0; c < 64; ++c) allF_out[c * SUP + g] = col[c];
    {
        float cnt = fmaxf(accum[35 * SUP + g], 1.0f);
        float rc = 1.0f / cnt;
#pragma unroll
        for (int c = 0; c < 3; ++c)
            xf_out[c * SUP + g] = accum[(32 + c) * SUP + g] * rc;
    }
    if (t == 0) {
        compute_col(accum, vit, b0 - 1, col);
#pragma unroll
        for (int c = 0; c < 64; ++c) L[0][c] = col[c];
    }
    if (t == 255) {
        compute_col(accum, vit, b0 + 256, col);
#pragma unroll
        for (int c = 0; c < 64; ++c) L[257][c] = col[c];
    }
    __syncthreads();

    float acc = bias[0];
#pragma unroll
    for (int c = 0; c < 64; ++c) {
        acc += sw[c * 3] * L[t][c] + sw[c * 3 + 1] * L[t + 1][c]
             + sw[c * 3 + 2] * L[t + 2][c];
    }
    z_out[b0 + t] = acc;
}

// ---------------------------------------------------------------------------
// K4: BN (batch stats over 2048) + sigmoid + gap. Single small block.
// out[0..2047] = result, out[2048] = gap.
// ---------------------------------------------------------------------------
__global__ __launch_bounds__(512) void k_head2(const float* __restrict__ z,
                                               const float* __restrict__ gamma,
                                               const float* __restrict__ beta,
                                               float* __restrict__ out) {
    __shared__ float red[8];
    __shared__ float bc[2];
    int tid = threadIdx.x;
    int lane = tid & 63, wid = tid >> 6;

    float zs[4];
#pragma unroll
    for (int j = 0; j < 4; ++j) zs[j] = z[j * 512 + tid];

    float s1 = zs[0] + zs[1] + zs[2] + zs[3];
#pragma unroll
    for (int o = 32; o > 0; o >>= 1) s1 += __shfl_down(s1, o);
    if (lane == 0) red[wid] = s1;
    __syncthreads();
    if (tid == 0) {
        float t = 0.f;
        for (int i = 0; i < 8; ++i) t += red[i];
        bc[0] = t / (float)SUP;
    }
    __syncthreads();
    float mu = bc[0];

    float s2 = 0.f;
#pragma unroll
    for (int j = 0; j < 4; ++j) { float d = zs[j] - mu; s2 += d * d; }
#pragma unroll
    for (int o = 32; o > 0; o >>= 1) s2 += __shfl_down(s2, o);
    __syncthreads();
    if (lane == 0) red[wid] = s2;
    __syncthreads();
    if (tid == 0) {
        float t = 0.f;
        for (int i = 0; i < 8; ++i) t += red[i];
        bc[1] = t / (float)SUP;
    }
    __syncthreads();
    float var = bc[1];

    float invstd = rsqrtf(var + 1e-5f);
    float gm = gamma[0], bt = beta[0];
    float gsum = 0.f;
#pragma unroll
    for (int j = 0; j < 4; ++j) {
        int p = j * 512 + tid;
        float zn = gm * (zs[j] - mu) * invstd + bt;
        float r = 1.0f / (1.0f + expf(-zn));
        out[p] = r;
        gsum += r;
    }
#pragma unroll
    for (int o = 32; o > 0; o >>= 1) gsum += __shfl_down(gsum, o);
    __syncthreads();
    if (lane == 0) red[wid] = gsum;
    __syncthreads();
    if (tid == 0) {
        float t = 0.f;
        for (int i = 0; i < 8; ++i) t += red[i];
        out[SUP] = t / (float)SUP;
    }
}

extern "C" void kernel_launch(void* const* d_in, const int* in_sizes, int n_in,
                              void* d_out, int out_size, void* d_ws, size_t ws_size,
                              hipStream_t stream) {
    const float* x     = (const float*)d_in[0];
    const float* conv  = (const float*)d_in[1];
    const float* vit   = (const float*)d_in[2];
    const int*   ids   = (const int*)d_in[3];
    const float* w     = (const float*)d_in[4];
    const float* b     = (const float*)d_in[5];
    const float* gamma = (const float*)d_in[6];
    const float* beta  = (const float*)d_in[7];
    float* out = (float*)d_out;

    int npix = in_sizes[3];  // B*H*W = 1048576

    float* inv = (float*)d_ws;                  // npix floats
    float* accum = inv + npix;                  // 36*SUP floats
    float* zbuf = accum + 36 * SUP;             // SUP floats
    __half* pbuf = (__half*)(zbuf + SUP);       // NXB*36*SUP halves (if fits)

    size_t need = ((size_t)npix + 36 * SUP + SUP) * sizeof(float)
                + (size_t)NXB * 36 * SUP * sizeof(__half);
    bool useP = ws_size >= need;

    if (!useP) hipMemsetAsync(accum, 0, 36 * SUP * sizeof(float), stream);

    int nquad = (npix + 3) / 4;
    k_invnorm<<<(nquad + 255) / 256, 256, 0, stream>>>(conv, inv, npix);

    dim3 g2(NXB, NG);
    k_segacc<<<g2, 512, 0, stream>>>(conv, x, ids, inv, accum,
                                     useP ? pbuf : (__half*)nullptr, npix);
    if (useP) {
        k_reduce<<<(36 * SUP / 8 + 255) / 256, 256, 0, stream>>>(pbuf, accum);
    }

    float* allF = out + SUP + 1;                // out offset 2049
    float* xf = allF + 64 * SUP;                // out offset 133121
    k_finalconv<<<SUP / 256, 256, 0, stream>>>(accum, vit, w, b, allF, xf, zbuf);

    k_head2<<<1, 512, 0, stream>>>(zbuf, gamma, beta, out);
}